// Round 1
// baseline (192.361 us; speedup 1.0000x reference)
//
#include <hip/hip_runtime.h>

#define BATCH 16
#define CH 64
#define NPIX 16384   // 128*128
#define TWOC 128

// ---------------------------------------------------------------------------
// Kernel 1: partial Gram matrices G[b][map][64][64] = sum_n V[c,n]*V[d,n]
// grid (32 chunks, 2 maps, 16 batches), block 256. Each block: 512 columns.
// ---------------------------------------------------------------------------
__global__ __launch_bounds__(256) void gram_kernel(
    const float* __restrict__ tmap, const float* __restrict__ rmap,
    float* __restrict__ G)
{
    __shared__ float tile[64][68];   // pad 68: loads conflict-free, reads <=2-way
    const int chunk = blockIdx.x;    // 0..31 -> 512 cols each
    const int map   = blockIdx.y;
    const int b     = blockIdx.z;
    const float* x = (map == 0 ? tmap : rmap) + (size_t)b * CH * NPIX + chunk * 512;
    const int t  = threadIdx.x;
    const int ti = t >> 4;           // 0..15 (row group, rows ti+16*i)
    const int tj = t & 15;           // 0..15 (col group, rows tj+16*j)

    float acc[4][4];
#pragma unroll
    for (int i = 0; i < 4; ++i)
#pragma unroll
        for (int j = 0; j < 4; ++j) acc[i][j] = 0.f;

    for (int tt = 0; tt < 8; ++tt) {
        const int col0 = tt * 64;
#pragma unroll
        for (int k = 0; k < 16; ++k) {
            int e = t + 256 * k;
            int c = e >> 6, col = e & 63;
            tile[c][col] = x[(size_t)c * NPIX + col0 + col];
        }
        __syncthreads();
#pragma unroll 8
        for (int n = 0; n < 64; n += 2) {
            float2 av[4], bv[4];
#pragma unroll
            for (int i = 0; i < 4; ++i) av[i] = *(const float2*)&tile[ti + 16 * i][n];
#pragma unroll
            for (int j = 0; j < 4; ++j) bv[j] = *(const float2*)&tile[tj + 16 * j][n];
#pragma unroll
            for (int i = 0; i < 4; ++i)
#pragma unroll
                for (int j = 0; j < 4; ++j) {
                    acc[i][j] += av[i].x * bv[j].x;
                    acc[i][j] += av[i].y * bv[j].y;
                }
        }
        __syncthreads();
    }
    float* Gp = G + ((size_t)(b * 2 + map) << 12);
#pragma unroll
    for (int i = 0; i < 4; ++i)
#pragma unroll
        for (int j = 0; j < 4; ++j)
            atomicAdd(&Gp[(ti + 16 * i) * 64 + (tj + 16 * j)], acc[i][j]);
}

// ---------------------------------------------------------------------------
// Kernel 2: softmax(rowmax - G) per row, then M[b] = [W1 + g*W1@r_attn | W2 + w*W2@t_attn]
// grid (16 batches), block 128.
// ---------------------------------------------------------------------------
__global__ __launch_bounds__(128) void finalize_kernel(
    const float* __restrict__ G, const float* __restrict__ gamma,
    const float* __restrict__ omega, const float* __restrict__ conv_w,
    float* __restrict__ M)
{
    __shared__ float attn[2][64][64];
    const int b = blockIdx.x;
    const int t = threadIdx.x;
    {
        const int map = t >> 6, i = t & 63;
        const float* Grow = G + ((size_t)(b * 2 + map) << 12) + i * 64;
        // softmax_j(rowmax - G[j]) == exp(rowmin - G[j]) / sum
        float mn = Grow[0];
        for (int j = 1; j < 64; ++j) mn = fminf(mn, Grow[j]);
        float s = 0.f;
        for (int j = 0; j < 64; ++j) s += expf(mn - Grow[j]);
        const float inv = 1.f / s;
        for (int j = 0; j < 64; ++j) attn[map][i][j] = expf(mn - Grow[j]) * inv;
    }
    __syncthreads();
    const float gam = gamma[0], om = omega[0];
    for (int idx = t; idx < CH * TWOC; idx += 128) {
        const int o = idx >> 7, k = idx & 127;
        const float* wrow = conv_w + o * TWOC;
        float v;
        if (k < 64) {
            float dot = 0.f;
            for (int c = 0; c < 64; ++c) dot += wrow[c] * attn[1][c][k];      // r_attn
            v = wrow[k] + gam * dot;
        } else {
            const int d = k - 64;
            float dot = 0.f;
            for (int c = 0; c < 64; ++c) dot += wrow[64 + c] * attn[0][c][d]; // t_attn
            v = wrow[k] + om * dot;
        }
        M[(size_t)b * (CH * TWOC) + idx] = v;
    }
}

// ---------------------------------------------------------------------------
// Kernel 3: out[b][o][n] = sum_k M[b][o][k] * fused[k][n] + conv_b[o]
// fused rows 0..63 = template, 64..127 = roi.
// grid (32 chunks of 512 cols, 16 batches), block 256.
// ---------------------------------------------------------------------------
__global__ __launch_bounds__(256) void out_kernel(
    const float* __restrict__ tmap, const float* __restrict__ rmap,
    const float* __restrict__ M, const float* __restrict__ conv_b,
    float* __restrict__ out)
{
    __shared__ float Ms[64][130];
    __shared__ float xt[128][68];
    const int b  = blockIdx.y;
    const int n0 = blockIdx.x * 512;
    const int t  = threadIdx.x;
    const int ti = t >> 4, tj = t & 15;

    for (int idx = t; idx < CH * TWOC; idx += 256)
        Ms[idx >> 7][idx & 127] = M[(size_t)b * (CH * TWOC) + idx];

    float bias[4];
#pragma unroll
    for (int i = 0; i < 4; ++i) bias[i] = conv_b[ti + 16 * i];

    const float* tb = tmap + (size_t)b * CH * NPIX;
    const float* rb = rmap + (size_t)b * CH * NPIX;

    for (int tc = 0; tc < 512; tc += 64) {
        const int colbase = n0 + tc;
#pragma unroll
        for (int k = 0; k < 32; ++k) {
            int e = t + 256 * k;
            int c = e >> 6, col = e & 63;
            const float* src = (c < 64) ? (tb + (size_t)c * NPIX)
                                        : (rb + (size_t)(c - 64) * NPIX);
            xt[c][col] = src[colbase + col];
        }
        __syncthreads();   // xt (and, first iter, Ms) ready

        float acc[4][4];
#pragma unroll
        for (int i = 0; i < 4; ++i)
#pragma unroll
            for (int cc = 0; cc < 4; ++cc) acc[i][cc] = 0.f;

#pragma unroll 4
        for (int k = 0; k < 128; k += 2) {
            float2 mv[4];
#pragma unroll
            for (int i = 0; i < 4; ++i) mv[i] = *(const float2*)&Ms[ti + 16 * i][k];
            float4 x0 = *(const float4*)&xt[k][tj * 4];
            float4 x1 = *(const float4*)&xt[k + 1][tj * 4];
#pragma unroll
            for (int i = 0; i < 4; ++i) {
                acc[i][0] += mv[i].x * x0.x; acc[i][0] += mv[i].y * x1.x;
                acc[i][1] += mv[i].x * x0.y; acc[i][1] += mv[i].y * x1.y;
                acc[i][2] += mv[i].x * x0.z; acc[i][2] += mv[i].y * x1.z;
                acc[i][3] += mv[i].x * x0.w; acc[i][3] += mv[i].y * x1.w;
            }
        }
        __syncthreads();   // done reading xt before next overwrite

#pragma unroll
        for (int i = 0; i < 4; ++i) {
            float4 o4;
            o4.x = acc[i][0] + bias[i];
            o4.y = acc[i][1] + bias[i];
            o4.z = acc[i][2] + bias[i];
            o4.w = acc[i][3] + bias[i];
            *(float4*)&out[((size_t)b * CH + ti + 16 * i) * NPIX + colbase + tj * 4] = o4;
        }
    }
}

// ---------------------------------------------------------------------------
extern "C" void kernel_launch(void* const* d_in, const int* in_sizes, int n_in,
                              void* d_out, int out_size, void* d_ws, size_t ws_size,
                              hipStream_t stream) {
    const float* tmap   = (const float*)d_in[0];
    const float* rmap   = (const float*)d_in[1];
    const float* gamma  = (const float*)d_in[2];
    const float* omega  = (const float*)d_in[3];
    const float* conv_w = (const float*)d_in[4];
    const float* conv_b = (const float*)d_in[5];
    float* out = (float*)d_out;

    // ws layout: G [16][2][4096] fp32 (512 KiB), then M [16][64][128] fp32 (512 KiB)
    float* G = (float*)d_ws;
    float* M = (float*)((char*)d_ws + (size_t)BATCH * 2 * 4096 * sizeof(float));

    hipMemsetAsync(d_ws, 0, (size_t)BATCH * 2 * 4096 * sizeof(float), stream);

    gram_kernel<<<dim3(32, 2, BATCH), 256, 0, stream>>>(tmap, rmap, G);
    finalize_kernel<<<dim3(BATCH), 128, 0, stream>>>(G, gamma, omega, conv_w, M);
    out_kernel<<<dim3(32, BATCH), 256, 0, stream>>>(tmap, rmap, M, conv_b, out);
}